// Round 1
// baseline (691.516 us; speedup 1.0000x reference)
//
#include <hip/hip_runtime.h>
#include <hip/hip_bf16.h>

// Problem constants (from setup_inputs)
#define BATCH 16
#define D_IN  1024
#define T_LEN 2048
#define K_CB  4096
#define D_CB  256

// d_out layout (float32, concatenated in return order)
#define ZI_OFF 0
#define ZQ_OFF (BATCH * D_CB * T_LEN)                 // 8388608
#define ZO_OFF (ZQ_OFF + BATCH * D_CB * T_LEN)       // 16777216
#define IDX_OFF (ZO_OFF + BATCH * D_IN * T_LEN)      // 50331648

typedef _Float16 half8 __attribute__((ext_vector_type(8)));
typedef _Float16 h4_t  __attribute__((ext_vector_type(4)));
typedef float floatx4 __attribute__((ext_vector_type(4)));

// ---------------- block reduce (256 threads) ----------------
__device__ __forceinline__ float block_sum256(float v) {
    __shared__ float sred[4];
    #pragma unroll
    for (int off = 32; off > 0; off >>= 1) v += __shfl_down(v, off, 64);
    if ((threadIdx.x & 63) == 0) sred[threadIdx.x >> 6] = v;
    __syncthreads();
    float r = sred[0] + sred[1] + sred[2] + sred[3];
    __syncthreads();
    return r;
}

// ---------------- weight norm: W[row] = g[row] * v[row] / ||v[row]|| ----------------
__global__ __launch_bounds__(256) void wn_rows(const float* __restrict__ v,
                                               const float* __restrict__ g,
                                               float* __restrict__ W, int N) {
    int row = blockIdx.x;
    const float* src = v + (size_t)row * N;
    float ss = 0.f;
    for (int c = threadIdx.x; c < N; c += 256) { float x = src[c]; ss += x * x; }
    ss = block_sum256(ss);
    float scale = g[row] * __frsqrt_rn(ss);
    for (int c = threadIdx.x; c < N; c += 256) W[(size_t)row * N + c] = src[c] * scale;
}

// ---------------- codebook: normalize rows + 2-way fp16 split, row-major [cw][k] ----------------
__global__ __launch_bounds__(256) void cb_prep(const float* __restrict__ cb,
                                               _Float16* __restrict__ c1,
                                               _Float16* __restrict__ c2) {
    int row = blockIdx.x;            // 0..4095
    int c = threadIdx.x;             // 0..255
    float x = cb[(size_t)row * D_CB + c];
    float ss = block_sum256(x * x);
    float scale = 1.0f / fmaxf(sqrtf(ss), 1e-12f);
    float v = x * scale;
    _Float16 h1 = (_Float16)v;
    _Float16 h2 = (_Float16)(v - (float)h1);
    c1[(size_t)row * D_CB + c] = h1;
    c2[(size_t)row * D_CB + c] = h2;
}

// ---------------- projection via f16-split MFMA ----------------
// Out[b,o,t] = sum_c W[o,c] * Z[b,c,t] + bias[o]
// Tile: 128 frames x 128 o, 256 threads = 4 waves (2 frame-halves x 2 o-halves),
// 64x64 per wave = 4x4 frags of 16x16x32 f16 MFMA. BK=32 (one MFMA k-step).
// 2-way f16 split, 3 products (a1b1 + a1b2 + a2b1) ~= fp32 precision.
// A-operand = Z frames (transposed+split during staging), B-operand = W (split).
template <int KDIM, int M>
__global__ __launch_bounds__(256, 2) void proj_mfma(const float* __restrict__ W,
                                                    const float* __restrict__ bias,
                                                    const float* __restrict__ Z,
                                                    float* __restrict__ Out) {
    // pad 40 f16 = 80 B row stride (odd multiple of 16B granule -> <=2-way on b128 reads)
    __shared__ _Float16 A_s[2][128][40];   // [split][frame][k]
    __shared__ _Float16 B_s[2][128][40];   // [split][o][k]

    const int tid  = threadIdx.x;
    const int wv   = tid >> 6;
    const int lane = tid & 63;
    const int lo4  = lane & 15, quad = lane >> 4;
    const int wm   = wv & 1,  wn  = wv >> 1;

    const int f0 = blockIdx.x * 128;       // global frame base (b*T_LEN + t)
    const int b  = f0 >> 11;               // f0 / T_LEN
    const int t0 = f0 & (T_LEN - 1);
    const int o0 = blockIdx.y * 128;
    const float* __restrict__ Zb = Z + (size_t)b * KDIM * T_LEN;

    const int a_g  = tid >> 5;             // c-quad group 0..7 (covers 32 k as 8x4)
    const int a_tl = tid & 31;             // frame lane (consecutive -> conflict-free LDS writes)

    float  pa[4][4];                       // [frame-block p][c offset j]
    float4 pb[4];

    floatx4 acc[4][4];
    #pragma unroll
    for (int i = 0; i < 4; i++)
        #pragma unroll
        for (int j = 0; j < 4; j++) acc[i][j] = (floatx4){0.f, 0.f, 0.f, 0.f};

    // prefetch kk = 0
    #pragma unroll
    for (int p = 0; p < 4; p++)
        #pragma unroll
        for (int j = 0; j < 4; j++)
            pa[p][j] = Zb[(size_t)(a_g * 4 + j) * T_LEN + t0 + p * 32 + a_tl];
    #pragma unroll
    for (int p = 0; p < 4; p++) {
        int idx = tid + p * 256;
        pb[p] = *(const float4*)&W[(size_t)(o0 + (idx >> 3)) * KDIM + (idx & 7) * 4];
    }

    for (int kk = 0; kk < KDIM; kk += 32) {
        // ---- stage prefetched tile (prev compute ended at trailing barrier) ----
        #pragma unroll
        for (int p = 0; p < 4; p++) {
            int f = p * 32 + a_tl;
            h4_t h1, h2;
            #pragma unroll
            for (int j = 0; j < 4; j++) {
                float v = pa[p][j];
                _Float16 x = (_Float16)v;
                h1[j] = x;
                h2[j] = (_Float16)(v - (float)x);
            }
            *(h4_t*)&A_s[0][f][a_g * 4] = h1;
            *(h4_t*)&A_s[1][f][a_g * 4] = h2;
        }
        #pragma unroll
        for (int p = 0; p < 4; p++) {
            int idx = tid + p * 256;
            int o = idx >> 3, k4 = (idx & 7) * 4;
            h4_t h1, h2;
            #pragma unroll
            for (int j = 0; j < 4; j++) {
                float v = ((const float*)&pb[p])[j];
                _Float16 x = (_Float16)v;
                h1[j] = x;
                h2[j] = (_Float16)(v - (float)x);
            }
            *(h4_t*)&B_s[0][o][k4] = h1;
            *(h4_t*)&B_s[1][o][k4] = h2;
        }
        __syncthreads();

        // ---- prefetch next K-tile while computing this one ----
        if (kk + 32 < KDIM) {
            #pragma unroll
            for (int p = 0; p < 4; p++)
                #pragma unroll
                for (int j = 0; j < 4; j++)
                    pa[p][j] = Zb[(size_t)(kk + 32 + a_g * 4 + j) * T_LEN + t0 + p * 32 + a_tl];
            #pragma unroll
            for (int p = 0; p < 4; p++) {
                int idx = tid + p * 256;
                pb[p] = *(const float4*)&W[(size_t)(o0 + (idx >> 3)) * KDIM + kk + 32 + (idx & 7) * 4];
            }
        }

        // ---- fragments + MFMA ----
        half8 a1[4], a2[4], b1[4], b2[4];
        #pragma unroll
        for (int mi = 0; mi < 4; mi++) {
            a1[mi] = *(const half8*)&A_s[0][wm * 64 + mi * 16 + lo4][quad * 8];
            a2[mi] = *(const half8*)&A_s[1][wm * 64 + mi * 16 + lo4][quad * 8];
        }
        #pragma unroll
        for (int ni = 0; ni < 4; ni++) {
            b1[ni] = *(const half8*)&B_s[0][wn * 64 + ni * 16 + lo4][quad * 8];
            b2[ni] = *(const half8*)&B_s[1][wn * 64 + ni * 16 + lo4][quad * 8];
        }
        #pragma unroll
        for (int mi = 0; mi < 4; mi++)
            #pragma unroll
            for (int ni = 0; ni < 4; ni++) {
                acc[mi][ni] = __builtin_amdgcn_mfma_f32_16x16x32_f16(a1[mi], b1[ni], acc[mi][ni], 0, 0, 0);
                acc[mi][ni] = __builtin_amdgcn_mfma_f32_16x16x32_f16(a1[mi], b2[ni], acc[mi][ni], 0, 0, 0);
                acc[mi][ni] = __builtin_amdgcn_mfma_f32_16x16x32_f16(a2[mi], b1[ni], acc[mi][ni], 0, 0, 0);
            }
        __syncthreads();
    }

    // epilogue: C layout col(o)=lane&15, row(frame)=quad*4+reg -> float4 along t
    #pragma unroll
    for (int ni = 0; ni < 4; ni++) {
        int o = o0 + wn * 64 + ni * 16 + lo4;
        float bv = bias[o];
        #pragma unroll
        for (int mi = 0; mi < 4; mi++) {
            int t = t0 + wm * 64 + mi * 16 + quad * 4;
            floatx4 r = acc[mi][ni];
            float4 st = make_float4(r[0] + bv, r[1] + bv, r[2] + bv, r[3] + bv);
            *(float4*)&Out[((size_t)b * M + o) * T_LEN + t] = st;
        }
    }
}

// ---------------- VQ via f16-split MFMA (unchanged, harness-verified) ----------------
__global__ __launch_bounds__(256) void vq_mfma(const float* __restrict__ z_i,
                                               const _Float16* __restrict__ cbn1,
                                               const _Float16* __restrict__ cbn2,
                                               const float* __restrict__ cb,
                                               float* __restrict__ z_q,
                                               float* __restrict__ idx_out) {
    __shared__ _Float16 e_s[2][32][264];   // splits x frame x k (pad 264: 2-way max)
    __shared__ _Float16 cb_s[2][128][72];  // splits x cw x k-chunk (pad 72: 2-way max)
    __shared__ float red_v[4][32];
    __shared__ int   red_i[4][32];
    __shared__ int   idx_s[32];

    const int tid  = threadIdx.x;
    const int wv   = tid >> 6;
    const int lane = tid & 63;
    const int lo4  = lane & 15, quad = lane >> 4;
    const int f0 = blockIdx.x * 32;
    const int b  = f0 >> 11;               // f0 / T_LEN
    const int t0 = f0 & (T_LEN - 1);

    // stage enc (fp32) -> 2-way fp16 split, transposed to [f][k]
    for (int i = tid; i < 32 * 256; i += 256) {
        int k = i >> 5, t = i & 31;
        float v = z_i[((size_t)(b * D_CB + k)) * T_LEN + t0 + t];
        _Float16 h1 = (_Float16)v;
        _Float16 h2 = (_Float16)(v - (float)h1);
        e_s[0][t][k] = h1;
        e_s[1][t][k] = h2;
    }

    float best_v[2][4];
    int   best_i[2][4];
    #pragma unroll
    for (int m = 0; m < 2; m++)
        #pragma unroll
        for (int r = 0; r < 4; r++) { best_v[m][r] = -3.4e38f; best_i[m][r] = 0; }

    __syncthreads();

    for (int n = 0; n < 32; n++) {
        const int cwg = n * 128;
        floatx4 acc[2][2];
        #pragma unroll
        for (int m = 0; m < 2; m++)
            #pragma unroll
            for (int t = 0; t < 2; t++) acc[m][t] = (floatx4){0.f, 0.f, 0.f, 0.f};

        // prefetch kc=0 into registers (s 0..3 -> split1, s 4..7 -> split2; no divergence)
        half8 pf[8];
        #pragma unroll
        for (int s = 0; s < 8; s++) {
            int c2 = tid + s * 256;
            const _Float16* src = (s < 4) ? cbn1 : cbn2;
            int rem = c2 & 1023, cw = rem >> 3, ko = (rem & 7) * 8;
            pf[s] = *(const half8*)(src + (size_t)(cwg + cw) * D_CB + ko);
        }

        for (int kc = 0; kc < 4; kc++) {
            // write prefetched tile into LDS (previous compute finished at trailing barrier)
            #pragma unroll
            for (int s = 0; s < 8; s++) {
                int c2 = tid + s * 256;
                int sp = (s < 4) ? 0 : 1;
                int rem = c2 & 1023, cw = rem >> 3, ko = (rem & 7) * 8;
                *(half8*)&cb_s[sp][cw][ko] = pf[s];
            }
            __syncthreads();
            // prefetch next stage while computing this one
            if (kc < 3) {
                #pragma unroll
                for (int s = 0; s < 8; s++) {
                    int c2 = tid + s * 256;
                    const _Float16* src = (s < 4) ? cbn1 : cbn2;
                    int rem = c2 & 1023, cw = rem >> 3, ko = (rem & 7) * 8;
                    pf[s] = *(const half8*)(src + (size_t)(cwg + cw) * D_CB + (kc + 1) * 64 + ko);
                }
            }
            #pragma unroll
            for (int ks = 0; ks < 2; ks++) {
                const int kb = kc * 64 + ks * 32 + quad * 8;  // enc k index
                const int kl = ks * 32 + quad * 8;            // cb tile k index
                half8 a1[2], a2[2], b1[2], b2[2];
                #pragma unroll
                for (int m = 0; m < 2; m++) {
                    a1[m] = *(const half8*)&e_s[0][m * 16 + lo4][kb];
                    a2[m] = *(const half8*)&e_s[1][m * 16 + lo4][kb];
                }
                #pragma unroll
                for (int t = 0; t < 2; t++) {
                    b1[t] = *(const half8*)&cb_s[0][wv * 32 + t * 16 + lo4][kl];
                    b2[t] = *(const half8*)&cb_s[1][wv * 32 + t * 16 + lo4][kl];
                }
                #pragma unroll
                for (int m = 0; m < 2; m++)
                    #pragma unroll
                    for (int t = 0; t < 2; t++) {
                        acc[m][t] = __builtin_amdgcn_mfma_f32_16x16x32_f16(a1[m], b1[t], acc[m][t], 0, 0, 0);
                        acc[m][t] = __builtin_amdgcn_mfma_f32_16x16x32_f16(a1[m], b2[t], acc[m][t], 0, 0, 0);
                        acc[m][t] = __builtin_amdgcn_mfma_f32_16x16x32_f16(a2[m], b1[t], acc[m][t], 0, 0, 0);
                    }
            }
            __syncthreads();
        }

        // fold this chunk's scores into running per-lane argmax
        // C/D layout: col(cw)=lane&15, row(frame)=quad*4+reg
        #pragma unroll
        for (int m = 0; m < 2; m++)
            #pragma unroll
            for (int t = 0; t < 2; t++) {
                int cwi = cwg + wv * 32 + t * 16 + lo4;
                #pragma unroll
                for (int r = 0; r < 4; r++) {
                    float v = acc[m][t][r];
                    if (v > best_v[m][r] || (v == best_v[m][r] && cwi < best_i[m][r])) {
                        best_v[m][r] = v; best_i[m][r] = cwi;
                    }
                }
            }
    }

    // reduce across the 16 column-lanes within each quad
    #pragma unroll
    for (int m = 0; m < 2; m++)
        #pragma unroll
        for (int r = 0; r < 4; r++) {
            float bv = best_v[m][r]; int bi = best_i[m][r];
            #pragma unroll
            for (int off = 8; off > 0; off >>= 1) {
                float ov = __shfl_down(bv, off, 16);
                int   oi = __shfl_down(bi, off, 16);
                if (ov > bv || (ov == bv && oi < bi)) { bv = ov; bi = oi; }
            }
            if (lo4 == 0) {
                red_v[wv][m * 16 + quad * 4 + r] = bv;
                red_i[wv][m * 16 + quad * 4 + r] = bi;
            }
        }
    __syncthreads();
    if (tid < 32) {
        float bv = red_v[0][tid]; int bi = red_i[0][tid];
        #pragma unroll
        for (int w = 1; w < 4; w++) {
            float ov = red_v[w][tid]; int oi = red_i[w][tid];
            if (ov > bv || (ov == bv && oi < bi)) { bv = ov; bi = oi; }
        }
        idx_s[tid] = bi;
        idx_out[f0 + tid] = (float)bi;
    }
    __syncthreads();

    // z_q[b,c,t0+f] = codebook[idx_f][c]
    for (int i = tid; i < 32 * 256; i += 256) {
        int k = i >> 5, t = i & 31;
        z_q[((size_t)(b * D_CB + k)) * T_LEN + t0 + t] = cb[(size_t)idx_s[t] * D_CB + k];
    }
}

extern "C" void kernel_launch(void* const* d_in, const int* in_sizes, int n_in,
                              void* d_out, int out_size, void* d_ws, size_t ws_size,
                              hipStream_t stream) {
    const float* z     = (const float*)d_in[0];
    const float* in_v  = (const float*)d_in[1];
    const float* in_g  = (const float*)d_in[2];
    const float* in_b  = (const float*)d_in[3];
    const float* out_v = (const float*)d_in[4];
    const float* out_g = (const float*)d_in[5];
    const float* out_b = (const float*)d_in[6];
    const float* cb    = (const float*)d_in[7];

    float* ws    = (float*)d_ws;
    float* W_in  = ws;                               // 256*1024 fp32
    float* W_out = ws + 262144;                      // 1024*256 fp32
    _Float16* cbn1 = (_Float16*)(ws + 524288);       // 4096*256 fp16 (2 MB)
    _Float16* cbn2 = (_Float16*)(ws + 1048576);      // 4096*256 fp16 (2 MB)

    float* out  = (float*)d_out;
    float* z_i  = out + ZI_OFF;
    float* z_q  = out + ZQ_OFF;
    float* z_o  = out + ZO_OFF;
    float* idxf = out + IDX_OFF;

    // weight-norm + codebook normalize/split
    wn_rows<<<D_CB, 256, 0, stream>>>(in_v, in_g, W_in, D_IN);
    wn_rows<<<D_IN, 256, 0, stream>>>(out_v, out_g, W_out, D_CB);
    cb_prep<<<K_CB, 256, 0, stream>>>(cb, cbn1, cbn2);

    // z_i = W_in @ z + in_b   (f16-split MFMA)
    proj_mfma<D_IN, D_CB><<<dim3((BATCH * T_LEN) / 128, D_CB / 128), 256, 0, stream>>>(W_in, in_b, z, z_i);

    // nearest codeword + z_q + indices (f16-split MFMA)
    vq_mfma<<<(BATCH * T_LEN) / 32, 256, 0, stream>>>(z_i, cbn1, cbn2, cb, z_q, idxf);

    // z_o = W_out @ z_q + out_b   (f16-split MFMA)
    proj_mfma<D_CB, D_IN><<<dim3((BATCH * T_LEN) / 128, D_IN / 128), 256, 0, stream>>>(W_out, out_b, z_q, z_o);
}

// Round 2
// 586.372 us; speedup vs baseline: 1.1793x; 1.1793x over previous
//
#include <hip/hip_runtime.h>
#include <hip/hip_bf16.h>

// Problem constants (from setup_inputs)
#define BATCH 16
#define D_IN  1024
#define T_LEN 2048
#define K_CB  4096
#define D_CB  256

// d_out layout (float32, concatenated in return order)
#define ZI_OFF 0
#define ZQ_OFF (BATCH * D_CB * T_LEN)                 // 8388608
#define ZO_OFF (ZQ_OFF + BATCH * D_CB * T_LEN)       // 16777216
#define IDX_OFF (ZO_OFF + BATCH * D_IN * T_LEN)      // 50331648

typedef _Float16 half8 __attribute__((ext_vector_type(8)));
typedef _Float16 h4_t  __attribute__((ext_vector_type(4)));
typedef float floatx4 __attribute__((ext_vector_type(4)));

// ---------------- block reduce (256 threads) ----------------
__device__ __forceinline__ float block_sum256(float v) {
    __shared__ float sred[4];
    #pragma unroll
    for (int off = 32; off > 0; off >>= 1) v += __shfl_down(v, off, 64);
    if ((threadIdx.x & 63) == 0) sred[threadIdx.x >> 6] = v;
    __syncthreads();
    float r = sred[0] + sred[1] + sred[2] + sred[3];
    __syncthreads();
    return r;
}

// ---------------- weight norm: W[row] = g[row] * v[row] / ||v[row]|| ----------------
__global__ __launch_bounds__(256) void wn_rows(const float* __restrict__ v,
                                               const float* __restrict__ g,
                                               float* __restrict__ W, int N) {
    int row = blockIdx.x;
    const float* src = v + (size_t)row * N;
    float ss = 0.f;
    for (int c = threadIdx.x; c < N; c += 256) { float x = src[c]; ss += x * x; }
    ss = block_sum256(ss);
    float scale = g[row] * __frsqrt_rn(ss);
    for (int c = threadIdx.x; c < N; c += 256) W[(size_t)row * N + c] = src[c] * scale;
}

// ---------------- codebook: normalize + 2-way fp16 split, packed in MFMA fragment order ----
// Packed layout (elem index, _Float16):
//   cbt[ (tt*16 + ks*2 + sp)*512 + lane*8 + j ]
// where tt = cw>>4 (16-cw tile), lo4 = cw&15, ks = k>>5 (k-step of 32),
// quad = (k>>3)&3, j = k&7, lane = quad*16 + lo4.
// A wave's B-fragment load for (tt,ks,sp) is then 64 lanes x 16B = 1 KB contiguous.
__global__ __launch_bounds__(256) void cb_prep(const float* __restrict__ cb,
                                               _Float16* __restrict__ cbt) {
    int row = blockIdx.x;            // cw: 0..4095
    int c = threadIdx.x;             // k:  0..255
    float x = cb[(size_t)row * D_CB + c];
    float ss = block_sum256(x * x);
    float scale = 1.0f / fmaxf(sqrtf(ss), 1e-12f);
    float v = x * scale;
    _Float16 h1 = (_Float16)v;
    _Float16 h2 = (_Float16)(v - (float)h1);
    int tt = row >> 4, lo4 = row & 15;
    int ks = c >> 5, quad = (c >> 3) & 3, j = c & 7;
    size_t base = ((size_t)(tt * 16 + ks * 2)) * 512 + (quad * 16 + lo4) * 8 + j;
    cbt[base] = h1;            // sp = 0
    cbt[base + 512] = h2;      // sp = 1
}

// ---------------- projection via f16-split MFMA (unchanged, harness-verified R1) ----------------
template <int KDIM, int M>
__global__ __launch_bounds__(256, 2) void proj_mfma(const float* __restrict__ W,
                                                    const float* __restrict__ bias,
                                                    const float* __restrict__ Z,
                                                    float* __restrict__ Out) {
    __shared__ _Float16 A_s[2][128][40];   // [split][frame][k]
    __shared__ _Float16 B_s[2][128][40];   // [split][o][k]

    const int tid  = threadIdx.x;
    const int wv   = tid >> 6;
    const int lane = tid & 63;
    const int lo4  = lane & 15, quad = lane >> 4;
    const int wm   = wv & 1,  wn  = wv >> 1;

    const int f0 = blockIdx.x * 128;
    const int b  = f0 >> 11;
    const int t0 = f0 & (T_LEN - 1);
    const int o0 = blockIdx.y * 128;
    const float* __restrict__ Zb = Z + (size_t)b * KDIM * T_LEN;

    const int a_g  = tid >> 5;
    const int a_tl = tid & 31;

    float  pa[4][4];
    float4 pb[4];

    floatx4 acc[4][4];
    #pragma unroll
    for (int i = 0; i < 4; i++)
        #pragma unroll
        for (int j = 0; j < 4; j++) acc[i][j] = (floatx4){0.f, 0.f, 0.f, 0.f};

    #pragma unroll
    for (int p = 0; p < 4; p++)
        #pragma unroll
        for (int j = 0; j < 4; j++)
            pa[p][j] = Zb[(size_t)(a_g * 4 + j) * T_LEN + t0 + p * 32 + a_tl];
    #pragma unroll
    for (int p = 0; p < 4; p++) {
        int idx = tid + p * 256;
        pb[p] = *(const float4*)&W[(size_t)(o0 + (idx >> 3)) * KDIM + (idx & 7) * 4];
    }

    for (int kk = 0; kk < KDIM; kk += 32) {
        #pragma unroll
        for (int p = 0; p < 4; p++) {
            int f = p * 32 + a_tl;
            h4_t h1, h2;
            #pragma unroll
            for (int j = 0; j < 4; j++) {
                float v = pa[p][j];
                _Float16 x = (_Float16)v;
                h1[j] = x;
                h2[j] = (_Float16)(v - (float)x);
            }
            *(h4_t*)&A_s[0][f][a_g * 4] = h1;
            *(h4_t*)&A_s[1][f][a_g * 4] = h2;
        }
        #pragma unroll
        for (int p = 0; p < 4; p++) {
            int idx = tid + p * 256;
            int o = idx >> 3, k4 = (idx & 7) * 4;
            h4_t h1, h2;
            #pragma unroll
            for (int j = 0; j < 4; j++) {
                float v = ((const float*)&pb[p])[j];
                _Float16 x = (_Float16)v;
                h1[j] = x;
                h2[j] = (_Float16)(v - (float)x);
            }
            *(h4_t*)&B_s[0][o][k4] = h1;
            *(h4_t*)&B_s[1][o][k4] = h2;
        }
        __syncthreads();

        if (kk + 32 < KDIM) {
            #pragma unroll
            for (int p = 0; p < 4; p++)
                #pragma unroll
                for (int j = 0; j < 4; j++)
                    pa[p][j] = Zb[(size_t)(kk + 32 + a_g * 4 + j) * T_LEN + t0 + p * 32 + a_tl];
            #pragma unroll
            for (int p = 0; p < 4; p++) {
                int idx = tid + p * 256;
                pb[p] = *(const float4*)&W[(size_t)(o0 + (idx >> 3)) * KDIM + kk + 32 + (idx & 7) * 4];
            }
        }

        half8 a1[4], a2[4], b1[4], b2[4];
        #pragma unroll
        for (int mi = 0; mi < 4; mi++) {
            a1[mi] = *(const half8*)&A_s[0][wm * 64 + mi * 16 + lo4][quad * 8];
            a2[mi] = *(const half8*)&A_s[1][wm * 64 + mi * 16 + lo4][quad * 8];
        }
        #pragma unroll
        for (int ni = 0; ni < 4; ni++) {
            b1[ni] = *(const half8*)&B_s[0][wn * 64 + ni * 16 + lo4][quad * 8];
            b2[ni] = *(const half8*)&B_s[1][wn * 64 + ni * 16 + lo4][quad * 8];
        }
        #pragma unroll
        for (int mi = 0; mi < 4; mi++)
            #pragma unroll
            for (int ni = 0; ni < 4; ni++) {
                acc[mi][ni] = __builtin_amdgcn_mfma_f32_16x16x32_f16(a1[mi], b1[ni], acc[mi][ni], 0, 0, 0);
                acc[mi][ni] = __builtin_amdgcn_mfma_f32_16x16x32_f16(a1[mi], b2[ni], acc[mi][ni], 0, 0, 0);
                acc[mi][ni] = __builtin_amdgcn_mfma_f32_16x16x32_f16(a2[mi], b1[ni], acc[mi][ni], 0, 0, 0);
            }
        __syncthreads();
    }

    #pragma unroll
    for (int ni = 0; ni < 4; ni++) {
        int o = o0 + wn * 64 + ni * 16 + lo4;
        float bv = bias[o];
        #pragma unroll
        for (int mi = 0; mi < 4; mi++) {
            int t = t0 + wm * 64 + mi * 16 + quad * 4;
            floatx4 r = acc[mi][ni];
            float4 st = make_float4(r[0] + bv, r[1] + bv, r[2] + bv, r[3] + bv);
            *(float4*)&Out[((size_t)b * M + o) * T_LEN + t] = st;
        }
    }
}

// ---------------- VQ v2: A (enc) in registers, B (codebook) direct from global ----------------
// Block = 32 frames, 4 waves. Wave wv owns codewords [wv*1024, wv*1024+1024) as 64 tiles of 16.
// No LDS and no barriers in the main loop. 3-product f16 split: e1c1 + e1c2 + e2c1.
__global__ __launch_bounds__(256, 2) void vq_mfma(const float* __restrict__ z_i,
                                                  const _Float16* __restrict__ cbt,
                                                  const float* __restrict__ cb,
                                                  float* __restrict__ z_q,
                                                  float* __restrict__ idx_out) {
    __shared__ _Float16 e_s[2][32][264];   // splits x frame x k (pad 264 halves)
    __shared__ float red_v[4][32];
    __shared__ int   red_i[4][32];
    __shared__ int   idx_s[32];

    const int tid  = threadIdx.x;
    const int wv   = tid >> 6;
    const int lane = tid & 63;
    const int lo4  = lane & 15, quad = lane >> 4;
    const int f0 = blockIdx.x * 32;
    const int b  = f0 >> 11;               // f0 / T_LEN
    const int t0 = f0 & (T_LEN - 1);

    // stage enc (fp32) -> 2-way fp16 split, transposed to [f][k]
    for (int i = tid; i < 32 * 256; i += 256) {
        int k = i >> 5, t = i & 31;
        float v = z_i[((size_t)(b * D_CB + k)) * T_LEN + t0 + t];
        _Float16 h1 = (_Float16)v;
        _Float16 h2 = (_Float16)(v - (float)h1);
        e_s[0][t][k] = h1;
        e_s[1][t][k] = h2;
    }
    __syncthreads();

    // hoist A-fragments (this lane's enc rows) into registers: 32 half8 = 128 VGPR
    half8 a1[2][8], a2[2][8];
    #pragma unroll
    for (int m = 0; m < 2; m++)
        #pragma unroll
        for (int ks = 0; ks < 8; ks++) {
            a1[m][ks] = *(const half8*)&e_s[0][m * 16 + lo4][ks * 32 + quad * 8];
            a2[m][ks] = *(const half8*)&e_s[1][m * 16 + lo4][ks * 32 + quad * 8];
        }

    float best_v[2][4];
    int   best_i[2][4];
    #pragma unroll
    for (int m = 0; m < 2; m++)
        #pragma unroll
        for (int r = 0; r < 4; r++) { best_v[m][r] = -3.4e38f; best_i[m][r] = 0; }

    const int tt0 = wv * 64;               // first 16-cw tile of this wave
    // B-fragment pointers: tile tt, k-step ks, split sp -> cbt + tt*8192 + ks*1024 + sp*512 + lane*8
    const _Float16* cb_lane = cbt + lane * 8;

    half8 b1[8], b2[8];
    #pragma unroll
    for (int ks = 0; ks < 8; ks++) {
        b1[ks] = *(const half8*)(cb_lane + (size_t)tt0 * 8192 + ks * 1024);
        b2[ks] = *(const half8*)(cb_lane + (size_t)tt0 * 8192 + ks * 1024 + 512);
    }

    for (int tt = tt0; tt < tt0 + 64; tt++) {
        floatx4 accA[2], accB[2];
        #pragma unroll
        for (int m = 0; m < 2; m++) { accA[m] = (floatx4){0.f,0.f,0.f,0.f}; accB[m] = (floatx4){0.f,0.f,0.f,0.f}; }

        const int ttn = (tt + 1 < tt0 + 64) ? tt + 1 : tt0;   // clamped prefetch target
        const _Float16* nb = cb_lane + (size_t)ttn * 8192;

        #pragma unroll
        for (int ks = 0; ks < 8; ks++) {
            half8 cb1 = b1[ks], cb2 = b2[ks];
            accA[0] = __builtin_amdgcn_mfma_f32_16x16x32_f16(a1[0][ks], cb1, accA[0], 0, 0, 0);
            accB[0] = __builtin_amdgcn_mfma_f32_16x16x32_f16(a1[0][ks], cb2, accB[0], 0, 0, 0);
            accA[0] = __builtin_amdgcn_mfma_f32_16x16x32_f16(a2[0][ks], cb1, accA[0], 0, 0, 0);
            accA[1] = __builtin_amdgcn_mfma_f32_16x16x32_f16(a1[1][ks], cb1, accA[1], 0, 0, 0);
            accB[1] = __builtin_amdgcn_mfma_f32_16x16x32_f16(a1[1][ks], cb2, accB[1], 0, 0, 0);
            accA[1] = __builtin_amdgcn_mfma_f32_16x16x32_f16(a2[1][ks], cb1, accA[1], 0, 0, 0);
            // reload this k-step's B for the next tile (slack ~ one full tile of MFMAs)
            b1[ks] = *(const half8*)(nb + ks * 1024);
            b2[ks] = *(const half8*)(nb + ks * 1024 + 512);
        }

        // fold: C/D layout col(cw)=lane&15, row(frame)=quad*4+reg
        const int cwi = tt * 16 + lo4;
        #pragma unroll
        for (int m = 0; m < 2; m++)
            #pragma unroll
            for (int r = 0; r < 4; r++) {
                float v = accA[m][r] + accB[m][r];
                if (v > best_v[m][r] || (v == best_v[m][r] && cwi < best_i[m][r])) {
                    best_v[m][r] = v; best_i[m][r] = cwi;
                }
            }
    }

    // reduce across the 16 column-lanes within each quad
    #pragma unroll
    for (int m = 0; m < 2; m++)
        #pragma unroll
        for (int r = 0; r < 4; r++) {
            float bv = best_v[m][r]; int bi = best_i[m][r];
            #pragma unroll
            for (int off = 8; off > 0; off >>= 1) {
                float ov = __shfl_down(bv, off, 16);
                int   oi = __shfl_down(bi, off, 16);
                if (ov > bv || (ov == bv && oi < bi)) { bv = ov; bi = oi; }
            }
            if (lo4 == 0) {
                red_v[wv][m * 16 + quad * 4 + r] = bv;
                red_i[wv][m * 16 + quad * 4 + r] = bi;
            }
        }
    __syncthreads();
    if (tid < 32) {
        float bv = red_v[0][tid]; int bi = red_i[0][tid];
        #pragma unroll
        for (int w = 1; w < 4; w++) {
            float ov = red_v[w][tid]; int oi = red_i[w][tid];
            if (ov > bv || (ov == bv && oi < bi)) { bv = ov; bi = oi; }
        }
        idx_s[tid] = bi;
        idx_out[f0 + tid] = (float)bi;
    }
    __syncthreads();

    // z_q[b,c,t0+f] = codebook[idx_f][c]
    for (int i = tid; i < 32 * 256; i += 256) {
        int k = i >> 5, t = i & 31;
        z_q[((size_t)(b * D_CB + k)) * T_LEN + t0 + t] = cb[(size_t)idx_s[t] * D_CB + k];
    }
}

extern "C" void kernel_launch(void* const* d_in, const int* in_sizes, int n_in,
                              void* d_out, int out_size, void* d_ws, size_t ws_size,
                              hipStream_t stream) {
    const float* z     = (const float*)d_in[0];
    const float* in_v  = (const float*)d_in[1];
    const float* in_g  = (const float*)d_in[2];
    const float* in_b  = (const float*)d_in[3];
    const float* out_v = (const float*)d_in[4];
    const float* out_g = (const float*)d_in[5];
    const float* out_b = (const float*)d_in[6];
    const float* cb    = (const float*)d_in[7];

    float* ws    = (float*)d_ws;
    float* W_in  = ws;                               // 256*1024 fp32 (1 MB)
    float* W_out = ws + 262144;                      // 1024*256 fp32 (1 MB)
    _Float16* cbt = (_Float16*)(ws + 524288);        // packed split codebook (4 MB)

    float* out  = (float*)d_out;
    float* z_i  = out + ZI_OFF;
    float* z_q  = out + ZQ_OFF;
    float* z_o  = out + ZO_OFF;
    float* idxf = out + IDX_OFF;

    // weight-norm + codebook normalize/split/pack
    wn_rows<<<D_CB, 256, 0, stream>>>(in_v, in_g, W_in, D_IN);
    wn_rows<<<D_IN, 256, 0, stream>>>(out_v, out_g, W_out, D_CB);
    cb_prep<<<K_CB, 256, 0, stream>>>(cb, cbt);

    // z_i = W_in @ z + in_b   (f16-split MFMA)
    proj_mfma<D_IN, D_CB><<<dim3((BATCH * T_LEN) / 128, D_CB / 128), 256, 0, stream>>>(W_in, in_b, z, z_i);

    // nearest codeword + z_q + indices (register-resident MFMA, no main-loop LDS)
    vq_mfma<<<(BATCH * T_LEN) / 32, 256, 0, stream>>>(z_i, cbt, cb, z_q, idxf);

    // z_o = W_out @ z_q + out_b   (f16-split MFMA)
    proj_mfma<D_CB, D_IN><<<dim3((BATCH * T_LEN) / 128, D_IN / 128), 256, 0, stream>>>(W_out, out_b, z_q, z_o);
}